// Round 7
// baseline (238.799 us; speedup 1.0000x reference)
//
#include <hip/hip_runtime.h>

#define BQ 2
#define DIMC 192
#define DINNER 384
#define LQ 4096
#define NST 16
#define XDBLP 48
#define NCHUNK 256
#define CS 16   // LQ / NCHUNK

// ---------------- K0: weight transforms -------------------------------------------
// WxT: 384x48 padded transpose of W_x. WoutP: paired-d layout of W_out:
// WoutP[((d2*3+cg)*64+lane)*2+par] = W_out[c][d], c=cg*64+lane, d=2*d2+par.
__global__ void k0_transpose(const float* __restrict__ Wx, const float* __restrict__ Wout,
                             float* __restrict__ WxT, float* __restrict__ WoutP) {
    int t = blockIdx.x * 256 + threadIdx.x;
    if (t < DINNER * XDBLP) {
        int d = t / XDBLP, k = t % XDBLP;
        WxT[t] = (k < 44) ? Wx[k * DINNER + d] : 0.f;
    }
    if (t < DIMC * DINNER) {
        int c = t / DINNER, d = t % DINNER;
        int d2 = d >> 1, par = d & 1, cg = c >> 6, lane = c & 63;
        WoutP[((d2 * 3 + cg) * 64 + lane) * 2 + par] = Wout[t];
    }
}

// ---------------- K1: xz = xf @ W_in — 512 threads, 8 waves share W-panel -----------
// grid (128 lb, 3 mb, 2 b), block 512. Tile 32 l x 256 m; wave owns l-quad,
// lane owns m-quad. Per c: 1 global dwordx4 (W) + 1 uniform ds_read_b128 + 16 FMA.
__global__ __launch_bounds__(512) void k1_inproj(const float* __restrict__ x,
                                                 const float* __restrict__ W_in,
                                                 float* __restrict__ xz) {
    __shared__ float xs[DIMC * 32];   // 24 KB, [c][ll]
    int b = blockIdx.z, lb = blockIdx.x, mb = blockIdx.y;
    int t = threadIdx.x;
    int l0 = lb * 32;
    const float* xb = x + (size_t)b * DIMC * LQ + l0;
    #pragma unroll
    for (int it = 0; it < 12; ++it) {
        int e = it * 512 + t;                // 6144 = 192*32
        int c = e >> 5, ll = e & 31;
        xs[e] = xb[(size_t)c * LQ + ll];     // 128B segments
    }
    __syncthreads();
    int lane = t & 63;
    int wq = __builtin_amdgcn_readfirstlane(t >> 6);   // wave's l-quad (0..7)
    int m0 = mb * 256 + lane * 4;
    float4 acc[4];
    #pragma unroll
    for (int j = 0; j < 4; ++j) acc[j] = make_float4(0.f, 0.f, 0.f, 0.f);
    const float* Wb = W_in + m0;
    #pragma unroll 4
    for (int c = 0; c < DIMC; ++c) {
        float4 wv = *(const float4*)(Wb + (size_t)c * 768);   // coalesced 1KB/wave
        float4 xa = *(const float4*)(xs + c * 32 + wq * 4);   // uniform broadcast
        #define K1FMA(J, XV) \
            acc[J].x = fmaf(wv.x, XV, acc[J].x); acc[J].y = fmaf(wv.y, XV, acc[J].y); \
            acc[J].z = fmaf(wv.z, XV, acc[J].z); acc[J].w = fmaf(wv.w, XV, acc[J].w);
        K1FMA(0, xa.x) K1FMA(1, xa.y) K1FMA(2, xa.z) K1FMA(3, xa.w)
        #undef K1FMA
    }
    #pragma unroll
    for (int j = 0; j < 4; ++j)
        *(float4*)(xz + (size_t)(b * LQ + l0 + wq * 4 + j) * 768 + m0) = acc[j];
}

// ---------------- K2: causal conv(4)+silu -> x_conv [b,l,d] AND x_convT [b,d,l] -----
// grid (256 lb, 2 b), block 384 (thread = d). Sliding window over 16-l tile.
__global__ __launch_bounds__(384) void k2_conv(const float* __restrict__ xz,
                                               const float* __restrict__ conv_w,
                                               const float* __restrict__ conv_b,
                                               float* __restrict__ x_conv,
                                               float* __restrict__ x_convT) {
    __shared__ float cs[16 * DINNER];   // 24.6 KB
    int b = blockIdx.y, lb = blockIdx.x;
    int l0 = lb * 16;
    int t = threadIdx.x;   // = d
    float4 w = *(const float4*)(conv_w + t * 4);
    float bias = conv_b[t];
    float xm3 = 0.f, xm2 = 0.f, xm1 = 0.f;
    #pragma unroll
    for (int i = 3; i >= 1; --i) {
        int l = l0 - i;
        float v = (l >= 0) ? xz[(size_t)(b * LQ + l) * 768 + t] : 0.f;
        xm3 = xm2; xm2 = xm1; xm1 = v;
    }
    #pragma unroll
    for (int ll = 0; ll < 16; ++ll) {
        int l = l0 + ll;
        float v = xz[(size_t)(b * LQ + l) * 768 + t];
        float acc = bias;
        acc = fmaf(w.x, xm3, acc);
        acc = fmaf(w.y, xm2, acc);
        acc = fmaf(w.z, xm1, acc);
        acc = fmaf(w.w, v, acc);
        float rr = acc / (1.f + __expf(-acc));
        x_conv[(size_t)(b * LQ + l) * DINNER + t] = rr;
        cs[ll * DINNER + t] = rr;
        xm3 = xm2; xm2 = xm1; xm1 = v;
    }
    __syncthreads();
    float* dst = x_convT + ((size_t)(b * DINNER) + t) * LQ + l0;
    #pragma unroll
    for (int q = 0; q < 16; q += 4) {
        float4 v = make_float4(cs[(q+0) * DINNER + t], cs[(q+1) * DINNER + t],
                               cs[(q+2) * DINNER + t], cs[(q+3) * DINNER + t]);
        *(float4*)(dst + q) = v;
    }
}

// ---------------- K3: x_dbl partials (split-K=4): p[ds][b,l,48] ---------------------
__global__ __launch_bounds__(256) void k3_xdbl(const float* __restrict__ x_convT,
                                               const float* __restrict__ WxT,
                                               float* __restrict__ xdp) {
    int b = blockIdx.z, ds = blockIdx.y, lb = blockIdx.x;
    int t = threadIdx.x;
    int lane = t & 63;
    int kg = __builtin_amdgcn_readfirstlane(t >> 6);
    int k0 = kg * 12;
    int l = lb * 64 + lane;
    const float* src = x_convT + (size_t)(b * DINNER + ds * 96) * LQ + l;
    float acc[12];
    #pragma unroll
    for (int i = 0; i < 12; ++i) acc[i] = 0.f;
    #pragma unroll 4
    for (int d = 0; d < 96; ++d) {
        float xv = src[(size_t)d * LQ];
        const float* Wr = WxT + (size_t)(ds * 96 + d) * XDBLP + k0;  // uniform
        #pragma unroll
        for (int i = 0; i < 12; ++i) acc[i] = fmaf(xv, Wr[i], acc[i]);
    }
    float* dst = xdp + (size_t)ds * (BQ * LQ * XDBLP) + (size_t)(b * LQ + l) * XDBLP + k0;
    #pragma unroll
    for (int i = 0; i < 12; i += 4)
        *(float4*)(dst + i) = make_float4(acc[i], acc[i+1], acc[i+2], acc[i+3]);
}

// ---------------- K5: scan pass A — local scan; emit hend, sumd, y_part, sdc --------
// grid (256 ch, 2 b), block 384 (thread = d).
__global__ __launch_bounds__(DINNER) void k5_scanA(const float* __restrict__ x_conv,
                                                   const float* __restrict__ xdp,
                                                   const float* __restrict__ W_dt,
                                                   const float* __restrict__ b_dt,
                                                   const float* __restrict__ A_log,
                                                   float* __restrict__ hend,
                                                   float* __restrict__ sumd,
                                                   float* __restrict__ ypart,
                                                   float* __restrict__ sdc) {
    __shared__ float xd[CS * XDBLP];   // 3 KB: dt|B|C rows for this chunk
    int b = blockIdx.y, ch = blockIdx.x;
    int l0 = ch * CS;
    int t = threadIdx.x;
    const size_t PD = (size_t)BQ * LQ * XDBLP;
    size_t base = (size_t)(b * LQ + l0) * XDBLP;
    for (int idx = t; idx < CS * XDBLP; idx += DINNER)
        xd[idx] = xdp[base + idx] + xdp[PD + base + idx]
                + xdp[2 * PD + base + idx] + xdp[3 * PD + base + idx];
    float wdt[12];
    #pragma unroll
    for (int r = 0; r < 12; r += 4) {
        float4 v = *(const float4*)(W_dt + t * 12 + r);
        wdt[r] = v.x; wdt[r+1] = v.y; wdt[r+2] = v.z; wdt[r+3] = v.w;
    }
    float bdt2 = 2.f * b_dt[t];
    float A[NST];
    #pragma unroll
    for (int n = 0; n < NST; ++n) A[n] = -__expf(A_log[t * NST + n]);
    __syncthreads();
    float h[NST];
    #pragma unroll
    for (int n = 0; n < NST; ++n) h[n] = 0.f;
    float sd = 0.f;
    for (int ll = 0; ll < CS; ++ll) {
        size_t gi = (size_t)(b * LQ + l0 + ll) * DINNER + t;
        float u = x_conv[gi];
        float d0 = bdt2, d1 = 0.f, d2 = 0.f;
        #pragma unroll
        for (int r = 0; r < 4; ++r) {
            d0 = fmaf(xd[ll * XDBLP + r], wdt[r], d0);
            d1 = fmaf(xd[ll * XDBLP + 4 + r], wdt[4 + r], d1);
            d2 = fmaf(xd[ll * XDBLP + 8 + r], wdt[8 + r], d2);
        }
        float dr = d0 + d1 + d2;
        float dl = fmaxf(dr, 0.f) + __logf(1.f + __expf(-fabsf(dr)));   // softplus
        sd += dl;
        sdc[gi] = sd;
        float du = dl * u;
        float yv = 0.f;
        #pragma unroll
        for (int n = 0; n < NST; ++n) {
            h[n] = fmaf(__expf(dl * A[n]), h[n], du * xd[ll * XDBLP + 12 + n]);
            yv = fmaf(h[n], xd[ll * XDBLP + 28 + n], yv);
        }
        ypart[gi] = yv;
    }
    size_t hb = ((size_t)(b * NCHUNK + ch) * DINNER + t) * NST;
    #pragma unroll
    for (int n = 0; n < NST; n += 4)
        *(float4*)(hend + hb + n) = make_float4(h[n], h[n+1], h[n+2], h[n+3]);
    sumd[(size_t)(b * NCHUNK + ch) * DINNER + t] = sd;
}

// ---------------- K6: chunk-carry combine, 16 segments x 16 chunks ------------------
// grid (384 d, 2 b), block 256 = 16 n x 16 segments.
__global__ __launch_bounds__(256) void k6_combine(const float* __restrict__ A_log,
                                                  const float* __restrict__ sumd,
                                                  const float* __restrict__ hend,
                                                  float* __restrict__ hin) {
    __shared__ float As[16][NST], Bs[16][NST];
    int d = blockIdx.x, b = blockIdx.y;
    int t = threadIdx.x;
    int n = t & 15, g = t >> 4;
    float A = -__expf(A_log[d * NST + n]);
    float ca = 1.f, cb = 0.f;
    #pragma unroll
    for (int i = 0; i < 16; ++i) {
        int ch = g * 16 + i;
        float a = __expf(A * sumd[(size_t)(b * NCHUNK + ch) * DINNER + d]);
        float bh = hend[((size_t)(b * NCHUNK + ch) * DINNER + d) * NST + n];
        ca *= a;
        cb = fmaf(a, cb, bh);
    }
    As[g][n] = ca; Bs[g][n] = cb;
    __syncthreads();
    float carry = 0.f;                       // h0 = 0
    for (int j = 0; j < g; ++j) carry = fmaf(As[j][n], carry, Bs[j][n]);
    #pragma unroll
    for (int i = 0; i < 16; ++i) {
        int ch = g * 16 + i;
        size_t idx = ((size_t)(b * NCHUNK + ch) * DINNER + d) * NST + n;
        hin[idx] = carry;
        float a = __expf(A * sumd[(size_t)(b * NCHUNK + ch) * DINNER + d]);
        carry = fmaf(a, carry, hend[idx]);
    }
}

// ---------------- K7: pass C — PARALLEL correction + gate, emit yT[b,d,l] -----------
// grid (256 ch, 2 b), block 384.
__global__ __launch_bounds__(DINNER) void k7_passC(const float* __restrict__ x_conv,
                                                   const float* __restrict__ xdp,
                                                   const float* __restrict__ A_log,
                                                   const float* __restrict__ hin,
                                                   const float* __restrict__ Dp,
                                                   const float* __restrict__ xz,
                                                   const float* __restrict__ ypart,
                                                   const float* __restrict__ sdc,
                                                   float* __restrict__ yT) {
    __shared__ float cxd[CS * NST];        // C rows, 1 KB
    __shared__ float ys[CS * DINNER];      // 24.6 KB
    int b = blockIdx.y, ch = blockIdx.x;
    int l0 = ch * CS;
    int t = threadIdx.x;
    const size_t PD = (size_t)BQ * LQ * XDBLP;
    for (int idx = t; idx < CS * NST; idx += DINNER) {
        int ll = idx >> 4, n = idx & 15;
        size_t r = (size_t)(b * LQ + l0 + ll) * XDBLP + 28 + n;
        cxd[idx] = xdp[r] + xdp[PD + r] + xdp[2 * PD + r] + xdp[3 * PD + r];
    }
    float A[NST];
    #pragma unroll
    for (int n = 0; n < NST; ++n) A[n] = -__expf(A_log[t * NST + n]);
    float carry[NST];
    size_t hb = ((size_t)(b * NCHUNK + ch) * DINNER + t) * NST;
    #pragma unroll
    for (int n = 0; n < NST; n += 4) {
        float4 v = *(const float4*)(hin + hb + n);
        carry[n] = v.x; carry[n+1] = v.y; carry[n+2] = v.z; carry[n+3] = v.w;
    }
    float Dd = Dp[t];
    __syncthreads();
    #pragma unroll 4
    for (int ll = 0; ll < CS; ++ll) {
        size_t gi = (size_t)(b * LQ + l0 + ll) * DINNER + t;
        size_t zr = (size_t)(b * LQ + l0 + ll) * 768 + 384 + t;
        float yv = ypart[gi];
        float sc = sdc[gi];
        float u  = x_conv[gi];
        float z  = xz[zr];
        #pragma unroll
        for (int n = 0; n < NST; ++n)
            yv = fmaf(__expf(A[n] * sc) * carry[n], cxd[ll * NST + n], yv);
        yv = fmaf(u, Dd, yv);
        float sig = 1.f / (1.f + __expf(-z));
        ys[ll * DINNER + t] = yv * (z * sig);
    }
    __syncthreads();
    float* dst = yT + ((size_t)(b * DINNER) + t) * LQ + l0;
    #pragma unroll
    for (int q = 0; q < CS; q += 4) {
        float4 v = make_float4(ys[(q+0) * DINNER + t], ys[(q+1) * DINNER + t],
                               ys[(q+2) * DINNER + t], ys[(q+3) * DINNER + t]);
        *(float4*)(dst + q) = v;
    }
}

// ---------------- K8: out partials — 16-l tile, paired-d weights --------------------
// grid (256 lt, 2 ds, 2 b) = 1024 blocks, block 256. Wave owns l-quad; lane owns
// c = lane + {0,64,128}. Per d-pair: 3 dwordx2 (W) + 2 uniform b128 (y) + 24 FMA.
__global__ __launch_bounds__(256) void k8_out(const float* __restrict__ yT,
                                              const float* __restrict__ WoutP,
                                              float* __restrict__ op0,
                                              float* __restrict__ op1) {
    __shared__ float yt[DIMC * 17];   // 13 KB; stage [d*16+ll] (192x16), transpose [c*17+ll]
    int lt = blockIdx.x, ds = blockIdx.y, b = blockIdx.z;
    int l0 = lt * 16;
    int t = threadIdx.x;
    const float* yb = yT + (size_t)(b * DINNER + ds * 192) * LQ + l0;
    #pragma unroll
    for (int it = 0; it < 12; ++it) {
        int e = it * 256 + t;                // 3072 = 192*16
        int d = e >> 4, ll = e & 15;
        yt[e] = yb[(size_t)d * LQ + ll];
    }
    __syncthreads();
    int lane = t & 63;
    int wq = __builtin_amdgcn_readfirstlane(t >> 6);   // wave's l-quad
    float acc[4][3];
    #pragma unroll
    for (int j = 0; j < 4; ++j)
        #pragma unroll
        for (int k = 0; k < 3; ++k) acc[j][k] = 0.f;
    const float* Wb = WoutP + (size_t)(ds * 96) * 3 * 128 + lane * 2;
    #pragma unroll 4
    for (int d2 = 0; d2 < 96; ++d2) {
        float4 y0 = *(const float4*)(yt + (2 * d2) * 16 + wq * 4);       // uniform
        float4 y1 = *(const float4*)(yt + (2 * d2 + 1) * 16 + wq * 4);
        float2 w0 = *(const float2*)(Wb + (size_t)(d2 * 3 + 0) * 128);
        float2 w1 = *(const float2*)(Wb + (size_t)(d2 * 3 + 1) * 128);
        float2 w2 = *(const float2*)(Wb + (size_t)(d2 * 3 + 2) * 128);
        #define K8FMA(J, V0, V1) \
            acc[J][0] = fmaf(w0.x, V0, fmaf(w0.y, V1, acc[J][0])); \
            acc[J][1] = fmaf(w1.x, V0, fmaf(w1.y, V1, acc[J][1])); \
            acc[J][2] = fmaf(w2.x, V0, fmaf(w2.y, V1, acc[J][2]));
        K8FMA(0, y0.x, y1.x) K8FMA(1, y0.y, y1.y) K8FMA(2, y0.z, y1.z) K8FMA(3, y0.w, y1.w)
        #undef K8FMA
    }
    __syncthreads();   // done reading stage layout
    #pragma unroll
    for (int k = 0; k < 3; ++k)
        #pragma unroll
        for (int j = 0; j < 4; ++j)
            yt[(lane + 64 * k) * 17 + wq * 4 + j] = acc[j][k];   // stride-17: conflict-free
    __syncthreads();
    float* op = ds ? op1 : op0;
    #pragma unroll
    for (int it = 0; it < 12; ++it) {
        int e = it * 256 + t;                // 3072 = 192 c x 16 l
        int c = e >> 4, ll = e & 15;
        op[((size_t)b * DIMC + c) * LQ + l0 + ll] = yt[c * 17 + ll];
    }
}

// ---------------- K9: out = op0 + op1 ----------------------------------------------
__global__ __launch_bounds__(256) void k9_sum(const float* __restrict__ op0,
                                              const float* __restrict__ op1,
                                              float* __restrict__ out) {
    size_t i = ((size_t)blockIdx.x * 256 + threadIdx.x) * 4;
    float4 a = *(const float4*)(op0 + i);
    float4 c = *(const float4*)(op1 + i);
    *(float4*)(out + i) = make_float4(a.x + c.x, a.y + c.y, a.z + c.z, a.w + c.w);
}

extern "C" void kernel_launch(void* const* d_in, const int* in_sizes, int n_in,
                              void* d_out, int out_size, void* d_ws, size_t ws_size,
                              hipStream_t stream) {
    const float* x      = (const float*)d_in[0];
    const float* W_in   = (const float*)d_in[1];
    const float* conv_w = (const float*)d_in[2];
    const float* conv_b = (const float*)d_in[3];
    const float* W_x    = (const float*)d_in[4];
    const float* W_dt   = (const float*)d_in[5];
    const float* b_dt   = (const float*)d_in[6];
    const float* A_log  = (const float*)d_in[7];
    const float* Dp     = (const float*)d_in[8];
    const float* W_out  = (const float*)d_in[9];
    float* out = (float*)d_out;

    const size_t NBL = (size_t)BQ * LQ * DINNER;     // 3,145,728
    float* w = (float*)d_ws;
    float* xz      = w; w += (size_t)BQ * LQ * 768;  // 6,291,456
    float* x_conv  = w; w += NBL;
    float* x_convT = w; w += NBL;                    // reused as yT after k3
    float* xdp     = w; w += 4 * (size_t)BQ * LQ * XDBLP;
    float* hend    = w; w += (size_t)BQ * NCHUNK * DINNER * NST;
    float* hin     = w; w += (size_t)BQ * NCHUNK * DINNER * NST;
    float* sumd    = w; w += (size_t)BQ * NCHUNK * DINNER;
    float* ypart   = w; w += NBL;
    float* sdcb    = w; w += NBL;
    float* op0     = w; w += (size_t)BQ * DIMC * LQ;
    float* op1     = w; w += (size_t)BQ * DIMC * LQ;
    float* WxT     = w; w += (size_t)DINNER * XDBLP;
    float* WoutP   = w; w += (size_t)DINNER * DIMC;
    float* yT = x_convT;   // x_convT dead after k3

    k0_transpose<<<288, 256, 0, stream>>>(W_x, W_out, WxT, WoutP);
    k1_inproj<<<dim3(128, 3, BQ), 512, 0, stream>>>(x, W_in, xz);
    k2_conv<<<dim3(256, BQ), 384, 0, stream>>>(xz, conv_w, conv_b, x_conv, x_convT);
    k3_xdbl<<<dim3(64, 4, BQ), 256, 0, stream>>>(x_convT, WxT, xdp);
    k5_scanA<<<dim3(NCHUNK, BQ), DINNER, 0, stream>>>(x_conv, xdp, W_dt, b_dt, A_log,
                                                      hend, sumd, ypart, sdcb);
    k6_combine<<<dim3(DINNER, BQ), 256, 0, stream>>>(A_log, sumd, hend, hin);
    k7_passC<<<dim3(NCHUNK, BQ), DINNER, 0, stream>>>(x_conv, xdp, A_log, hin, Dp,
                                                      xz, ypart, sdcb, yT);
    k8_out<<<dim3(256, 2, BQ), 256, 0, stream>>>(yT, WoutP, op0, op1);
    k9_sum<<<(BQ * DIMC * LQ) / 1024, 256, 0, stream>>>(op0, op1, out);
}